// Round 1
// baseline (835.186 us; speedup 1.0000x reference)
//
#include <hip/hip_runtime.h>
#include <math.h>

// Batched 256-point complex DFT as 16x16 four-step FFT (no W reads, no matmul).
// Frame stride in LDS padded 256 -> 264 floats: all strided phases are 2-way
// bank aliased (free), float4 phases stay 16B-aligned.
#define FS 264

__device__ __forceinline__ void dft16(float* xr, float* xi) {
  // 16-point DFT, natural-order in/out, radix-4 x radix-4.
  // Twiddles w16^k = cos(pi k/8) - i sin(pi k/8), k = b*c <= 9.
  constexpr float TWR[10] = {1.f, 0.9238795325f, 0.7071067812f, 0.3826834324f, 0.f,
                             -0.3826834324f, -0.7071067812f, -0.9238795325f, -1.f,
                             -0.9238795325f};
  constexpr float TWI[10] = {0.f, -0.3826834324f, -0.7071067812f, -0.9238795325f, -1.f,
                             -0.9238795325f, -0.7071067812f, -0.3826834324f, 0.f,
                             0.3826834324f};
  float yr[16], yi[16];
#pragma unroll
  for (int b = 0; b < 4; ++b) {
    float x0r = xr[b],      x0i = xi[b];
    float x1r = xr[b + 4],  x1i = xi[b + 4];
    float x2r = xr[b + 8],  x2i = xi[b + 8];
    float x3r = xr[b + 12], x3i = xi[b + 12];
    float t0r = x0r + x2r, t0i = x0i + x2i;
    float t1r = x0r - x2r, t1i = x0i - x2i;
    float t2r = x1r + x3r, t2i = x1i + x3i;
    float t3r = x1r - x3r, t3i = x1i - x3i;
    // store as y[c*4 + b]
    yr[0 + b]  = t0r + t2r;  yi[0 + b]  = t0i + t2i;   // c=0
    yr[8 + b]  = t0r - t2r;  yi[8 + b]  = t0i - t2i;   // c=2
    yr[4 + b]  = t1r + t3i;  yi[4 + b]  = t1i - t3r;   // c=1: t1 - i*t3
    yr[12 + b] = t1r - t3i;  yi[12 + b] = t1i + t3r;   // c=3: t1 + i*t3
  }
#pragma unroll
  for (int c = 0; c < 4; ++c) {
    float zr[4], zi[4];
#pragma unroll
    for (int b = 0; b < 4; ++b) {
      const int k = b * c;  // <= 9, compile-time after unroll
      float ar = yr[c * 4 + b], ai = yi[c * 4 + b];
      zr[b] = ar * TWR[k] - ai * TWI[k];
      zi[b] = ar * TWI[k] + ai * TWR[k];
    }
    float t0r = zr[0] + zr[2], t0i = zi[0] + zi[2];
    float t1r = zr[0] - zr[2], t1i = zi[0] - zi[2];
    float t2r = zr[1] + zr[3], t2i = zi[1] + zi[3];
    float t3r = zr[1] - zr[3], t3i = zi[1] - zi[3];
    // out[c + 4d]
    xr[c]      = t0r + t2r;  xi[c]      = t0i + t2i;   // d=0
    xr[c + 8]  = t0r - t2r;  xi[c + 8]  = t0i - t2i;   // d=2
    xr[c + 4]  = t1r + t3i;  xi[c + 4]  = t1i - t3r;   // d=1
    xr[c + 12] = t1r - t3i;  xi[c + 12] = t1i + t3r;   // d=3
  }
}

__global__ __launch_bounds__(256, 4) void dft256_kernel(
    const float* __restrict__ xr, const float* __restrict__ xi,
    float* __restrict__ out, size_t half) {
  __shared__ __align__(16) float sA[16 * FS];
  __shared__ __align__(16) float sB[16 * FS];
  const int t = threadIdx.x;
  const size_t blk_off = (size_t)blockIdx.x * 4096;  // 16 frames * 256

  // Stage 0: coalesced global -> LDS (float4). Each wave writes one frame
  // (1 KB contiguous) per iteration.
  const float4* xr4 = (const float4*)(xr + blk_off);
  const float4* xi4 = (const float4*)(xi + blk_off);
  float4* sA4 = (float4*)sA;
  float4* sB4 = (float4*)sB;
#pragma unroll
  for (int i = 0; i < 4; ++i) {
    int g = t + (i << 8);
    int l = (g >> 6) * 66 + (g & 63);  // FS/4 = 66 float4 per frame
    sA4[l] = xr4[g];
    sB4[l] = xi4[g];
  }
  __syncthreads();

  const int f = t >> 4;   // local frame 0..15
  const int b = t & 15;   // column role (stage 1) == row role c (stage 2)
  const int fb = f * FS;

  // Stage 1: column DFT-16 over a, input x[16a + b]  (2-way banked: free)
  float vr[16], vi[16];
#pragma unroll
  for (int a = 0; a < 16; ++a) {
    vr[a] = sA[fb + a * 16 + b];
    vi[a] = sB[fb + a * 16 + b];
  }
  dft16(vr, vi);

  // Twiddle Z[c] = Y[c] * w256^{b c}; base via one sincos, then chained cmul.
  float swb, cwb;
  __sincosf(-6.283185307179586f * (float)b * (1.0f / 256.0f), &swb, &cwb);
  float twr = 1.f, twi = 0.f;
#pragma unroll
  for (int c = 0; c < 16; ++c) {
    float ar = vr[c], ai = vi[c];
    vr[c] = ar * twr - ai * twi;
    vi[c] = ar * twi + ai * twr;
    float ntr = twr * cwb - twi * swb;
    twi = twr * swb + twi * cwb;
    twr = ntr;
  }
  __syncthreads();  // all column reads done before overwrite

  // Transpose: Z stored [c*16 + b]
#pragma unroll
  for (int c = 0; c < 16; ++c) {
    sA[fb + c * 16 + b] = vr[c];
    sB[fb + c * 16 + b] = vi[c];
  }
  __syncthreads();

  // Stage 2: row DFT-16 over b at fixed c (= this thread's b), contiguous float4 reads
  {
    const int base = fb + b * 16;
#pragma unroll
    for (int j = 0; j < 4; ++j) {
      float4 r  = *(const float4*)&sA[base + 4 * j];
      float4 im = *(const float4*)&sB[base + 4 * j];
      vr[4 * j + 0] = r.x;  vr[4 * j + 1] = r.y;  vr[4 * j + 2] = r.z;  vr[4 * j + 3] = r.w;
      vi[4 * j + 0] = im.x; vi[4 * j + 1] = im.y; vi[4 * j + 2] = im.z; vi[4 * j + 3] = im.w;
    }
  }
  dft16(vr, vi);
  __syncthreads();  // all row reads done before overwrite

  // X[c + 16d], scaled by 1/sqrt(256) = 1/16, back to natural order in LDS
#pragma unroll
  for (int d = 0; d < 16; ++d) {
    sA[fb + d * 16 + b] = vr[d] * 0.0625f;
    sB[fb + d * 16 + b] = vi[d] * 0.0625f;
  }
  __syncthreads();

  // Coalesced LDS -> global (real block, then imag block of d_out)
  float4* outr4 = (float4*)(out + blk_off);
  float4* outi4 = (float4*)(out + half + blk_off);
#pragma unroll
  for (int i = 0; i < 4; ++i) {
    int g = t + (i << 8);
    int l = (g >> 6) * 66 + (g & 63);
    outr4[g] = sA4[l];
    outi4[g] = sB4[l];
  }
}

extern "C" void kernel_launch(void* const* d_in, const int* in_sizes, int n_in,
                              void* d_out, int out_size, void* d_ws, size_t ws_size,
                              hipStream_t stream) {
  const float* xr = (const float*)d_in[0];
  const float* xi = (const float*)d_in[1];
  // d_in[2]/d_in[3] (W_real/W_imag) intentionally unused: FFT twiddles are exact.
  float* out = (float*)d_out;
  const size_t half = (size_t)in_sizes[0];       // B*N = 67108864
  const int blocks = (int)(half / 4096);         // 16 frames per 256-thread block
  dft256_kernel<<<blocks, 256, 0, stream>>>(xr, xi, out, half);
}